// Round 6
// baseline (439.776 us; speedup 1.0000x reference)
//
#include <hip/hip_runtime.h>
#include <math.h>

#define B_  4
#define S_  2048
#define D_  1024
#define H_  16
#define DH_ 64
#define M_  (B_*S_)

typedef unsigned short ushort_t;
typedef __attribute__((ext_vector_type(8))) __bf16 bf16x8;
typedef __attribute__((ext_vector_type(4))) float f32x4;
typedef __attribute__((ext_vector_type(8))) unsigned short us8;
typedef __attribute__((ext_vector_type(4))) unsigned short us4;

__device__ __forceinline__ ushort_t f2bf(float f) {
    unsigned int u = __float_as_uint(f);
    u = (u + 0x7fffu + ((u >> 16) & 1u)) >> 16;   // RNE
    return (ushort_t)u;
}
__device__ __forceinline__ float bf2f(ushort_t u) {
    return __uint_as_float(((unsigned int)u) << 16);
}

// async global->LDS, 16B per lane, wave-uniform LDS base (HW: base + lane*16)
#define GLD16(gp, lp) __builtin_amdgcn_global_load_lds( \
    (const __attribute__((address_space(1))) void*)(gp), \
    (__attribute__((address_space(3))) void*)(lp), 16, 0, 0)

#define WAIT_VM0()   __builtin_amdgcn_s_waitcnt(0x0F70)  // vmcnt(0) only
#define WAIT_VM4()   __builtin_amdgcn_s_waitcnt(0x0F74)  // vmcnt(4) only
#define WAIT_VM8()   __builtin_amdgcn_s_waitcnt(0x0F78)  // vmcnt(8) only
#define MEMFENCE()   asm volatile("" ::: "memory")
#define BAR()        do { MEMFENCE(); __builtin_amdgcn_s_barrier(); MEMFENCE(); } while (0)

// ---------------------------------------------------------------------------
// merged fp32 -> bf16 converter: blocks 0..4095 convert x (8.4M elems),
// blocks 4096+k*512.. convert weight k (1M elems each), k = 0..3.
// ---------------------------------------------------------------------------
__global__ __launch_bounds__(256)
void cvt_all(const float* __restrict__ x,
             const float* __restrict__ w0, const float* __restrict__ w1,
             const float* __restrict__ w2, const float* __restrict__ w3,
             ushort_t* __restrict__ xd, ushort_t* __restrict__ wd)
{
    const int bid = blockIdx.x;
    const float* s;
    ushort_t* d;
    int i;
    if (bid < 4096) {
        s = x; d = xd; i = bid * 2048 + threadIdx.x * 8;
    } else {
        const int k = (bid - 4096) >> 9;
        const int r = (bid - 4096) & 511;
        s = (k == 0) ? w0 : (k == 1) ? w1 : (k == 2) ? w2 : w3;
        d = wd + (size_t)k * (D_ * D_);
        i = r * 2048 + threadIdx.x * 8;
    }
    float4 a = *(const float4*)(s + i);
    float4 b = *(const float4*)(s + i + 4);
    us8 r8;
    r8[0] = f2bf(a.x); r8[1] = f2bf(a.y); r8[2] = f2bf(a.z); r8[3] = f2bf(a.w);
    r8[4] = f2bf(b.x); r8[5] = f2bf(b.y); r8[6] = f2bf(b.z); r8[7] = f2bf(b.w);
    *(us8*)(d + i) = r8;
}

// ---------------------------------------------------------------------------
// MFMA GEMM: Y = A @ Bw^T + bias.  A:[M,K] bf16, Bw:[N,K] bf16 (torch weight).
// 128x128 tile, BK=32, 256 thr = 4 waves (2x2), 4x4 16x16x32 MFMAs per wave.
// TRIPLE-BUFFERED staging, prefetch depth 2 (vmcnt(8)) — R5 post-mortem:
// depth-1 double-buffer REGRESSED 77->96us (exposed staging latency +
// register squeeze from launch_bounds(256,5)).  This depth-2/48KB/3-blk
// config is the measured local optimum for K=1024; do not re-litigate
// without a new mechanism.  SQ_LDS_BANK_CONFLICT ~6.29M = inherent wave64
// b128 issue cost (4/read, banks already even at 8/bank) — not fixable.
// mode 0: N=3072 fused QKV -> scatter Q(bf16, *0.125*log2e)/K(bf16)/V^T(bf16)
// mode 1: N=1024 -> bf16 Yb[m*1024+n]
// ---------------------------------------------------------------------------
__global__ __launch_bounds__(256)
void gemm_mfma(const ushort_t* __restrict__ A, const ushort_t* __restrict__ Bw,
               const float* __restrict__ bias0, const float* __restrict__ bias1,
               const float* __restrict__ bias2,
               ushort_t* __restrict__ Yb, ushort_t* __restrict__ Qo,
               ushort_t* __restrict__ Ko, ushort_t* __restrict__ Vo,
               int K, int mode)
{
    __shared__ __align__(16) ushort_t As[3][128 * 32];
    __shared__ __align__(16) ushort_t Bs[3][128 * 32];
    const int t = threadIdx.x;
    const int lane = t & 63, wave = t >> 6;
    const int wm = wave >> 1, wn = wave & 1;
    const int m0 = blockIdx.x * 128, n0 = blockIdx.y * 128;
    const int quad = lane >> 4, l15 = lane & 15;

    const int ch0 = wave * 2, ch1 = wave * 2 + 1;
    const int srow = lane >> 2;                        // 0..15
    const int scol = 8 * ((lane & 3) ^ (srow & 3));    // swizzled 16B slot
    const ushort_t* Ap0 = A  + (size_t)(m0 + ch0 * 16 + srow) * K + scol;
    const ushort_t* Ap1 = A  + (size_t)(m0 + ch1 * 16 + srow) * K + scol;
    const ushort_t* Bp0 = Bw + (size_t)(n0 + ch0 * 16 + srow) * K + scol;
    const ushort_t* Bp1 = Bw + (size_t)(n0 + ch1 * 16 + srow) * K + scol;

    f32x4 acc[4][4] = {};

    // prefetch slabs 0,1 into buffers 0,1
    GLD16(Ap0, As[0] + ch0 * 512);
    GLD16(Ap1, As[0] + ch1 * 512);
    GLD16(Bp0, Bs[0] + ch0 * 512);
    GLD16(Bp1, Bs[0] + ch1 * 512);
    GLD16(Ap0 + 32, As[1] + ch0 * 512);
    GLD16(Ap1 + 32, As[1] + ch1 * 512);
    GLD16(Bp0 + 32, Bs[1] + ch0 * 512);
    GLD16(Bp1 + 32, Bs[1] + ch1 * 512);

    // frag-read slot offset: logical slot = quad, phys = quad ^ (row&3);
    // row = 16*i + l15 -> row&3 = l15&3.
    const int skq = 8 * (quad ^ (l15 & 3));

    const int nk = K >> 5;
    for (int ki = 0; ki < nk; ki++) {
        const int buf = ki % 3;
        if (ki + 2 < nk) {
            const int k2 = (ki + 2) << 5;
            const int b2 = (ki + 2) % 3;
            GLD16(Ap0 + k2, As[b2] + ch0 * 512);
            GLD16(Ap1 + k2, As[b2] + ch1 * 512);
            GLD16(Bp0 + k2, Bs[b2] + ch0 * 512);
            GLD16(Bp1 + k2, Bs[b2] + ch1 * 512);
            WAIT_VM8();     // own slab-ki loads landed; 8 (2 slabs) in flight
        } else if (ki + 1 < nk) {
            WAIT_VM4();
        } else {
            WAIT_VM0();
        }
        BAR();

        bf16x8 af[4], bfr[4];
        #pragma unroll
        for (int i = 0; i < 4; i++)
            af[i] = *(const bf16x8*)(As[buf] + (64 * wm + 16 * i + l15) * 32 + skq);
        #pragma unroll
        for (int j = 0; j < 4; j++)
            bfr[j] = *(const bf16x8*)(Bs[buf] + (64 * wn + 16 * j + l15) * 32 + skq);
        #pragma unroll
        for (int i = 0; i < 4; i++)
            #pragma unroll
            for (int j = 0; j < 4; j++)
                acc[i][j] = __builtin_amdgcn_mfma_f32_16x16x32_bf16(af[i], bfr[j], acc[i][j], 0, 0, 0);

        BAR();    // all reads of buf done before overwrite
    }

    // epilogue — C/D layout: row = quad*4+r, col = l15
    #pragma unroll
    for (int j = 0; j < 4; j++) {
        const int n = n0 + 64 * wn + 16 * j + l15;
        if (mode == 1) {
            const float bv = bias0[n];
            #pragma unroll
            for (int i = 0; i < 4; i++) {
                const int mrow = m0 + 64 * wm + 16 * i + quad * 4;
                ushort_t* yp = Yb + (size_t)mrow * D_ + n;
                #pragma unroll
                for (int r = 0; r < 4; r++)
                    yp[(size_t)r * D_] = f2bf(acc[i][j][r] + bv);
            }
        } else {
            const int sel = n >> 10, nn = n & 1023;
            const int hh = nn >> 6, dd = nn & 63;
            const float bv = (sel == 0 ? bias0 : (sel == 1 ? bias1 : bias2))[nn];
            // Q pre-scaled by 0.125*log2(e) so attention exp is exp2-native
            const float scl = (sel == 0) ? 0.18033688f : 1.0f;
            #pragma unroll
            for (int i = 0; i < 4; i++) {
                const int mrow = m0 + 64 * wm + 16 * i + quad * 4;
                const int b = mrow >> 11;
                const int ss = mrow & (S_ - 1);
                if (sel == 2) {
                    // V^T [B,H,dh,S]: r is contiguous -> one us4 store
                    us4 pk;
                    #pragma unroll
                    for (int r = 0; r < 4; r++)
                        pk[r] = f2bf(acc[i][j][r] + bv);
                    *(us4*)(Vo + (((size_t)b * H_ + hh) * DH_ + dd) * S_ + ss) = pk;
                } else {
                    ushort_t* dst = (sel == 0) ? Qo : Ko;
                    #pragma unroll
                    for (int r = 0; r < 4; r++) {
                        const float v = (acc[i][j][r] + bv) * scl;
                        dst[(((size_t)b * H_ + hh) * S_ + ss + r) * DH_ + dd] = f2bf(v);
                    }
                }
            }
        }
    }
}

// ---------------------------------------------------------------------------
// MFMA flash attention (causal), transposed-score, STATIC-MAX softmax.
//   S^T = K·Q^T  (C/D: row=key=quad*4+r, col=query=l15);  O^T = V^T·P^T.
// Q pre-scaled by 0.125*log2e -> p = exp2(s' - 16) via accumulator init -16.
// R6: reg-staged SINGLE K/V LDS buffer (T14 async-split): per-lane us8 global
// loads issued at loop top (in flight across the whole compute phase), then
// barrier -> ds_write_b128 -> barrier.  Same swizzled layout as before (the
// write side applies the pre-swizzled address the global source already had,
// so the frag-read path is unchanged).  LDS 50KB -> 34KB => 4 blocks/CU.
// Grid 64 x 16: x = bh (L2 locality), y -> qt = 15 - y (longest first).
// ---------------------------------------------------------------------------
__global__ __launch_bounds__(256, 4)
void attn_mfma(const ushort_t* __restrict__ Qb, const ushort_t* __restrict__ Kb,
               const ushort_t* __restrict__ Vt, ushort_t* __restrict__ outb)
{
    __shared__ __align__(16) ushort_t Ks[64 * 64];
    __shared__ __align__(16) ushort_t Vs[64 * 64];
    __shared__ __align__(16) ushort_t Ps[8][16 * 72];   // [wave*2+g][16q][64k+pad]
    const int t = threadIdx.x, lane = t & 63, w = t >> 6;
    const int bh = blockIdx.x;             // 0..63  (b*16+h)
    const int qt = 15 - (int)blockIdx.y;   // longest first
    const int quad = lane >> 4, l15 = lane & 15;
    const int rw = 32 * w;                 // wave's first query within q-tile

    const int c0 = 2 * w, c1 = 2 * w + 1;
    const int srow = lane >> 3;                   // 0..7 row within chunk
    const int scol = 8 * ((lane & 7) ^ srow);     // XOR-8 swizzled col (ushort)
    const ushort_t* KgB = Kb + (size_t)bh * S_ * DH_;
    const ushort_t* VgB = Vt + (size_t)bh * DH_ * S_;
    const ushort_t* Kg0 = KgB + (size_t)(c0 * 8 + srow) * DH_ + scol;
    const ushort_t* Kg1 = KgB + (size_t)(c1 * 8 + srow) * DH_ + scol;
    const ushort_t* Vg0 = VgB + (size_t)(c0 * 8 + srow) * S_ + scol;
    const ushort_t* Vg1 = VgB + (size_t)(c1 * 8 + srow) * S_ + scol;
    ushort_t* pw0 = Ps[w * 2 + 0];
    ushort_t* pw1 = Ps[w * 2 + 1];
    const int b = bh >> 4, hh = bh & (H_ - 1);

    const int q0 = qt * 128;

    const ushort_t* qp = Qb + ((size_t)bh * S_ + q0 + rw + l15) * DH_ + quad * 8;
    const bf16x8 qf00 = *(const bf16x8*)(qp);
    const bf16x8 qf01 = *(const bf16x8*)(qp + 32);
    const bf16x8 qf10 = *(const bf16x8*)(qp + 16 * DH_);
    const bf16x8 qf11 = *(const bf16x8*)(qp + 16 * DH_ + 32);

    f32x4 o0[4] = {}, o1[4] = {};
    float la0 = 0.f, la1 = 0.f;        // per-lane partial row-sum of P

    // prologue: stage tile 0 via registers (compiler inserts the vmcnt wait)
    {
        const us8 rk0 = *(const us8*)(Kg0);
        const us8 rk1 = *(const us8*)(Kg1);
        const us8 rv0 = *(const us8*)(Vg0);
        const us8 rv1 = *(const us8*)(Vg1);
        *(us8*)(Ks + c0 * 512 + lane * 8) = rk0;
        *(us8*)(Ks + c1 * 512 + lane * 8) = rk1;
        *(us8*)(Vs + c0 * 512 + lane * 8) = rv0;
        *(us8*)(Vs + c1 * 512 + lane * 8) = rv1;
    }
    BAR();

    const int qg00 = q0 + rw;          // g=0 first query
    const int qg10 = q0 + rw + 16;     // g=1 first query
    const int last = 2 * qt + 1;

    for (int kt = 0; kt <= last; kt++) {
        const int k0 = kt * 64;
        const bool pre = (kt < last);

        // issue next tile's loads NOW; they fly during the whole compute phase
        us8 nk0, nk1, nv0, nv1;
        if (pre) {
            const size_t ko = (size_t)(k0 + 64) * DH_;
            nk0 = *(const us8*)(Kg0 + ko);
            nk1 = *(const us8*)(Kg1 + ko);
            nv0 = *(const us8*)(Vg0 + k0 + 64);
            nv1 = *(const us8*)(Vg1 + k0 + 64);
        }

        if (k0 <= qg10 + 15) {         // wave has at least one unmasked query
            const bool a0 = (k0 <= qg00 + 15);
            const ushort_t* kb = Ks;
            const ushort_t* vb = Vs;
            const int xr = l15 & 7;    // swizzle term (row&7) for frag reads

            bf16x8 kf[4][2];
            #pragma unroll
            for (int ct = 0; ct < 4; ct++)
                #pragma unroll
                for (int h = 0; h < 2; h++)
                    kf[ct][h] = *(const bf16x8*)(kb + (ct * 16 + l15) * 64 +
                                                 8 * ((h * 4 + quad) ^ xr));

            // scores with C preloaded to -16 (static softmax shift)
            const f32x4 cinit = { -16.f, -16.f, -16.f, -16.f };
            f32x4 sc0[4], sc1[4];
            #pragma unroll
            for (int ct = 0; ct < 4; ct++) { sc0[ct] = cinit; sc1[ct] = cinit; }
            __builtin_amdgcn_s_setprio(1);
            #pragma unroll
            for (int ct = 0; ct < 4; ct++) {
                sc1[ct] = __builtin_amdgcn_mfma_f32_16x16x32_bf16(kf[ct][0], qf10, sc1[ct], 0, 0, 0);
                sc1[ct] = __builtin_amdgcn_mfma_f32_16x16x32_bf16(kf[ct][1], qf11, sc1[ct], 0, 0, 0);
            }
            if (a0) {
                #pragma unroll
                for (int ct = 0; ct < 4; ct++) {
                    sc0[ct] = __builtin_amdgcn_mfma_f32_16x16x32_bf16(kf[ct][0], qf00, sc0[ct], 0, 0, 0);
                    sc0[ct] = __builtin_amdgcn_mfma_f32_16x16x32_bf16(kf[ct][1], qf01, sc0[ct], 0, 0, 0);
                }
            }
            __builtin_amdgcn_s_setprio(0);

            bf16x8 vf[4][2];
            #pragma unroll
            for (int mt = 0; mt < 4; mt++)
                #pragma unroll
                for (int h = 0; h < 2; h++)
                    vf[mt][h] = *(const bf16x8*)(vb + (mt * 16 + l15) * 64 +
                                                 8 * ((h * 4 + quad) ^ xr));

            if (k0 + 63 > qg10) {      // causal mask: diagonal band only
                const int qq = qg10 + l15;
                #pragma unroll
                for (int ct = 0; ct < 4; ct++) {
                    const int key = k0 + ct * 16 + quad * 4;
                    #pragma unroll
                    for (int r = 0; r < 4; r++)
                        if (key + r > qq) sc1[ct][r] = -1e30f;
                }
            }
            if (a0 && k0 + 63 > qg00) {
                const int qq = qg00 + l15;
                #pragma unroll
                for (int ct = 0; ct < 4; ct++) {
                    const int key = k0 + ct * 16 + quad * 4;
                    #pragma unroll
                    for (int r = 0; r < 4; r++)
                        if (key + r > qq) sc0[ct][r] = -1e30f;
                }
            }

            // p = exp2(score - 16); accumulate per-lane l; truncation-pack
            #pragma unroll
            for (int ct = 0; ct < 4; ct++) {
                us4 pk;
                #pragma unroll
                for (int r = 0; r < 4; r++) {
                    const float p = exp2f(sc1[ct][r]);
                    la1 += p;
                    pk[r] = (ushort_t)(__float_as_uint(p) >> 16);
                }
                *(us4*)(pw1 + l15 * 72 + ct * 16 + quad * 4) = pk;
            }
            if (a0) {
                #pragma unroll
                for (int ct = 0; ct < 4; ct++) {
                    us4 pk;
                    #pragma unroll
                    for (int r = 0; r < 4; r++) {
                        const float p = exp2f(sc0[ct][r]);
                        la0 += p;
                        pk[r] = (ushort_t)(__float_as_uint(p) >> 16);
                    }
                    *(us4*)(pw0 + l15 * 72 + ct * 16 + quad * 4) = pk;
                }
            }

            // O^T += V^T · P^T  (B-frag: n=query=l15, k=key=h*32+quad*8+j)
            __builtin_amdgcn_s_setprio(1);
            const bf16x8 pf10 = *(const bf16x8*)(pw1 + l15 * 72 + quad * 8);
            const bf16x8 pf11 = *(const bf16x8*)(pw1 + l15 * 72 + 32 + quad * 8);
            #pragma unroll
            for (int mt = 0; mt < 4; mt++) {
                o1[mt] = __builtin_amdgcn_mfma_f32_16x16x32_bf16(vf[mt][0], pf10, o1[mt], 0, 0, 0);
                o1[mt] = __builtin_amdgcn_mfma_f32_16x16x32_bf16(vf[mt][1], pf11, o1[mt], 0, 0, 0);
            }
            if (a0) {
                const bf16x8 pf00 = *(const bf16x8*)(pw0 + l15 * 72 + quad * 8);
                const bf16x8 pf01 = *(const bf16x8*)(pw0 + l15 * 72 + 32 + quad * 8);
                #pragma unroll
                for (int mt = 0; mt < 4; mt++) {
                    o0[mt] = __builtin_amdgcn_mfma_f32_16x16x32_bf16(vf[mt][0], pf00, o0[mt], 0, 0, 0);
                    o0[mt] = __builtin_amdgcn_mfma_f32_16x16x32_bf16(vf[mt][1], pf01, o0[mt], 0, 0, 0);
                }
            }
            __builtin_amdgcn_s_setprio(0);
        }

        if (pre) {
            BAR();                     // all waves done reading Ks/Vs
            *(us8*)(Ks + c0 * 512 + lane * 8) = nk0;   // compiler waits vmcnt
            *(us8*)(Ks + c1 * 512 + lane * 8) = nk1;
            *(us8*)(Vs + c0 * 512 + lane * 8) = nv0;
            *(us8*)(Vs + c1 * 512 + lane * 8) = nv1;
            BAR();                     // new tile visible to all
        }
    }

    // epilogue: reduce l across quads once; normalize; bf16 stores
    {
        la0 += __shfl_xor(la0, 16);
        la1 += __shfl_xor(la1, 16);
        la0 += __shfl_xor(la0, 32);
        la1 += __shfl_xor(la1, 32);
        const float inv0 = 1.0f / la0, inv1 = 1.0f / la1;
        const int query0 = q0 + rw + l15;
        ushort_t* ob0 = outb + ((size_t)(b * S_ + query0)) * D_ + hh * DH_ + quad * 4;
        ushort_t* ob1 = ob0 + (size_t)16 * D_;
        #pragma unroll
        for (int mt = 0; mt < 4; mt++) {
            us4 r0, r1;
            #pragma unroll
            for (int r = 0; r < 4; r++) {
                r0[r] = f2bf(o0[mt][r] * inv0);
                r1[r] = f2bf(o1[mt][r] * inv1);
            }
            *(us4*)(ob0 + mt * 16) = r0;
            *(us4*)(ob1 + mt * 16) = r1;
        }
    }
}

// ---------------------------------------------------------------------------
// LN1: out_bf = LayerNorm(X_f32 + R_bf16) * g + b   (bf16 output only)
// R6: wave-per-row (4 rows/block, grid 2048).  16 elems/lane, coalesced
// strided float4/us4 accesses, __shfl_xor butterfly reduction.  No LDS, no
// __syncthreads — the old per-row-block version was latency-bound on the
// 2-stage LDS reduction (8192 tiny blocks).
// ---------------------------------------------------------------------------
__global__ __launch_bounds__(256)
void ln_f32bf(const float* __restrict__ X, const ushort_t* __restrict__ R,
              const float* __restrict__ g, const float* __restrict__ bia,
              ushort_t* __restrict__ out_bf)
{
    const int wid = threadIdx.x >> 6, lane = threadIdx.x & 63;
    const int row = blockIdx.x * 4 + wid;
    const float*   xr = X + (size_t)row * D_;
    const ushort_t* rr = R + (size_t)row * D_;

    float s[16];
    float sum = 0.f, sq = 0.f;
    #pragma unroll
    for (int k = 0; k < 4; k++) {
        const int off = k * 256 + lane * 4;
        const float4 xv = *(const float4*)(xr + off);
        const us4    rv = *(const us4*)(rr + off);
        const float v0 = xv.x + bf2f(rv[0]);
        const float v1 = xv.y + bf2f(rv[1]);
        const float v2 = xv.z + bf2f(rv[2]);
        const float v3 = xv.w + bf2f(rv[3]);
        s[k*4+0] = v0; s[k*4+1] = v1; s[k*4+2] = v2; s[k*4+3] = v3;
        sum += v0 + v1 + v2 + v3;
        sq  += v0*v0 + v1*v1 + v2*v2 + v3*v3;
    }
    #pragma unroll
    for (int off = 1; off < 64; off <<= 1) {
        sum += __shfl_xor(sum, off);
        sq  += __shfl_xor(sq,  off);
    }
    const float mean = sum * (1.0f / D_);
    const float inv  = rsqrtf(sq * (1.0f / D_) - mean * mean + 1e-5f);

    ushort_t* orow = out_bf + (size_t)row * D_;
    #pragma unroll
    for (int k = 0; k < 4; k++) {
        const int off = k * 256 + lane * 4;
        const float4 gv = *(const float4*)(g + off);
        const float4 bv = *(const float4*)(bia + off);
        us4 ob;
        ob[0] = f2bf((s[k*4+0] - mean) * inv * gv.x + bv.x);
        ob[1] = f2bf((s[k*4+1] - mean) * inv * gv.y + bv.y);
        ob[2] = f2bf((s[k*4+2] - mean) * inv * gv.z + bv.z);
        ob[3] = f2bf((s[k*4+3] - mean) * inv * gv.w + bv.w);
        *(us4*)(orow + off) = ob;
    }
}

// ---------------------------------------------------------------------------
// LN2: out_f32 = LayerNorm(Hb_bf16 + Yb_bf16) * g + b   (wave-per-row, R6)
// ---------------------------------------------------------------------------
__global__ __launch_bounds__(256)
void ln_bfbf(const ushort_t* __restrict__ Hb, const ushort_t* __restrict__ Yb,
             const float* __restrict__ g, const float* __restrict__ bia,
             float* __restrict__ outf)
{
    const int wid = threadIdx.x >> 6, lane = threadIdx.x & 63;
    const int row = blockIdx.x * 4 + wid;
    const ushort_t* hr = Hb + (size_t)row * D_;
    const ushort_t* yr = Yb + (size_t)row * D_;

    float s[16];
    float sum = 0.f, sq = 0.f;
    #pragma unroll
    for (int k = 0; k < 4; k++) {
        const int off = k * 256 + lane * 4;
        const us4 hv = *(const us4*)(hr + off);
        const us4 yv = *(const us4*)(yr + off);
        const float v0 = bf2f(hv[0]) + bf2f(yv[0]);
        const float v1 = bf2f(hv[1]) + bf2f(yv[1]);
        const float v2 = bf2f(hv[2]) + bf2f(yv[2]);
        const float v3 = bf2f(hv[3]) + bf2f(yv[3]);
        s[k*4+0] = v0; s[k*4+1] = v1; s[k*4+2] = v2; s[k*4+3] = v3;
        sum += v0 + v1 + v2 + v3;
        sq  += v0*v0 + v1*v1 + v2*v2 + v3*v3;
    }
    #pragma unroll
    for (int off = 1; off < 64; off <<= 1) {
        sum += __shfl_xor(sum, off);
        sq  += __shfl_xor(sq,  off);
    }
    const float mean = sum * (1.0f / D_);
    const float inv  = rsqrtf(sq * (1.0f / D_) - mean * mean + 1e-5f);

    float* orow = outf + (size_t)row * D_;
    #pragma unroll
    for (int k = 0; k < 4; k++) {
        const int off = k * 256 + lane * 4;
        const float4 gv = *(const float4*)(g + off);
        const float4 bv = *(const float4*)(bia + off);
        float4 o;
        o.x = (s[k*4+0] - mean) * inv * gv.x + bv.x;
        o.y = (s[k*4+1] - mean) * inv * gv.y + bv.y;
        o.z = (s[k*4+2] - mean) * inv * gv.z + bv.z;
        o.w = (s[k*4+3] - mean) * inv * gv.w + bv.w;
        *(float4*)(orow + off) = o;
    }
}

// ---------------------------------------------------------------------------
extern "C" void kernel_launch(void* const* d_in, const int* in_sizes, int n_in,
                              void* d_out, int out_size, void* d_ws, size_t ws_size,
                              hipStream_t stream)
{
    const float* x      = (const float*)d_in[0];
    const float* wq_w   = (const float*)d_in[1];
    const float* wq_b   = (const float*)d_in[2];
    const float* wk_w   = (const float*)d_in[3];
    const float* wk_b   = (const float*)d_in[4];
    const float* wv_w   = (const float*)d_in[5];
    const float* wv_b   = (const float*)d_in[6];
    const float* ln1_g  = (const float*)d_in[7];
    const float* ln1_b  = (const float*)d_in[8];
    const float* lin1_w = (const float*)d_in[9];
    const float* lin1_b = (const float*)d_in[10];
    const float* ln2_g  = (const float*)d_in[11];
    const float* ln2_b  = (const float*)d_in[12];
    float* out = (float*)d_out;

    char* base = (char*)d_ws;
    // ws layout (aliased through the pipeline):
    //   [0   ,16M): x_bf   -> attn_bf (x_bf dead after QKV GEMM)
    //   [16M ,24M): w_bf (wq|wk|wv|lin1)
    //   [24M ,40M): Qbf  -> h_bf   (Qbf dead after attention)
    //   [40M ,56M): Kbf  -> y_bf   (Kbf dead after attention)
    //   [56M ,72M): Vtp
    ushort_t* x_bf    = (ushort_t*)(base);
    ushort_t* attn_bf = (ushort_t*)(base);
    ushort_t* w_bf    = (ushort_t*)(base + 16777216);
    ushort_t* Qbf     = (ushort_t*)(base + 25165824);
    ushort_t* h_bf    = (ushort_t*)(base + 25165824);
    ushort_t* Kbf     = (ushort_t*)(base + 41943040);
    ushort_t* y_bf    = (ushort_t*)(base + 41943040);
    ushort_t* Vtp     = (ushort_t*)(base + 58720256);

    cvt_all<<<dim3(4096 + 4 * 512), 256, 0, stream>>>(
        x, wq_w, wk_w, wv_w, lin1_w, x_bf, w_bf);

    gemm_mfma<<<dim3(M_ / 128, 3072 / 128), 256, 0, stream>>>(
        x_bf, w_bf, wq_b, wk_b, wv_b, nullptr, Qbf, Kbf, Vtp, D_, 0);

    attn_mfma<<<dim3(64, 16), 256, 0, stream>>>(Qbf, Kbf, Vtp, attn_bf);

    ln_f32bf<<<dim3(M_ / 4), 256, 0, stream>>>(x, attn_bf, ln1_g, ln1_b, h_bf);

    gemm_mfma<<<dim3(M_ / 128, D_ / 128), 256, 0, stream>>>(
        h_bf, w_bf + 3 * D_ * D_, lin1_b, nullptr, nullptr, y_bf, nullptr, nullptr, nullptr, D_, 1);

    ln_bfbf<<<dim3(M_ / 4), 256, 0, stream>>>(h_bf, y_bf, ln2_g, ln2_b, out);
}

// Round 8
// 286.108 us; speedup vs baseline: 1.5371x; 1.5371x over previous
//
#include <hip/hip_runtime.h>
#include <math.h>

#define B_  4
#define S_  2048
#define D_  1024
#define H_  16
#define DH_ 64
#define M_  (B_*S_)

typedef unsigned short ushort_t;
typedef __attribute__((ext_vector_type(8))) __bf16 bf16x8;
typedef __attribute__((ext_vector_type(4))) float f32x4;
typedef __attribute__((ext_vector_type(8))) unsigned short us8;
typedef __attribute__((ext_vector_type(4))) unsigned short us4;

__device__ __forceinline__ ushort_t f2bf(float f) {
    unsigned int u = __float_as_uint(f);
    u = (u + 0x7fffu + ((u >> 16) & 1u)) >> 16;   // RNE
    return (ushort_t)u;
}
__device__ __forceinline__ float bf2f(ushort_t u) {
    return __uint_as_float(((unsigned int)u) << 16);
}

// async global->LDS, 16B per lane, wave-uniform LDS base (HW: base + lane*16)
#define GLD16(gp, lp) __builtin_amdgcn_global_load_lds( \
    (const __attribute__((address_space(1))) void*)(gp), \
    (__attribute__((address_space(3))) void*)(lp), 16, 0, 0)

#define WAIT_VM0()   __builtin_amdgcn_s_waitcnt(0x0F70)  // vmcnt(0) only
#define WAIT_VM4()   __builtin_amdgcn_s_waitcnt(0x0F74)  // vmcnt(4) only
#define WAIT_VM8()   __builtin_amdgcn_s_waitcnt(0x0F78)  // vmcnt(8) only
#define MEMFENCE()   asm volatile("" ::: "memory")
#define BAR()        do { MEMFENCE(); __builtin_amdgcn_s_barrier(); MEMFENCE(); } while (0)

// ---------------------------------------------------------------------------
// merged fp32 -> bf16 converter: blocks 0..4095 convert x (8.4M elems),
// blocks 4096+k*512.. convert weight k (1M elems each), k = 0..3.
// ---------------------------------------------------------------------------
__global__ __launch_bounds__(256)
void cvt_all(const float* __restrict__ x,
             const float* __restrict__ w0, const float* __restrict__ w1,
             const float* __restrict__ w2, const float* __restrict__ w3,
             ushort_t* __restrict__ xd, ushort_t* __restrict__ wd)
{
    const int bid = blockIdx.x;
    const float* s;
    ushort_t* d;
    int i;
    if (bid < 4096) {
        s = x; d = xd; i = bid * 2048 + threadIdx.x * 8;
    } else {
        const int k = (bid - 4096) >> 9;
        const int r = (bid - 4096) & 511;
        s = (k == 0) ? w0 : (k == 1) ? w1 : (k == 2) ? w2 : w3;
        d = wd + (size_t)k * (D_ * D_);
        i = r * 2048 + threadIdx.x * 8;
    }
    float4 a = *(const float4*)(s + i);
    float4 b = *(const float4*)(s + i + 4);
    us8 r8;
    r8[0] = f2bf(a.x); r8[1] = f2bf(a.y); r8[2] = f2bf(a.z); r8[3] = f2bf(a.w);
    r8[4] = f2bf(b.x); r8[5] = f2bf(b.y); r8[6] = f2bf(b.z); r8[7] = f2bf(b.w);
    *(us8*)(d + i) = r8;
}

// ---------------------------------------------------------------------------
// MFMA GEMM: Y = A @ Bw^T + bias.  A:[M,K] bf16, Bw:[N,K] bf16 (torch weight).
// 128x128 tile, BK=32, 256 thr = 4 waves (2x2), 4x4 16x16x32 MFMAs per wave.
// TRIPLE-BUFFERED staging, prefetch depth 2 (vmcnt(8)) — R5 post-mortem:
// depth-1 double-buffer REGRESSED 77->96us.  This depth-2/48KB/3-blk config
// is the measured local optimum for K=1024; do not re-litigate without a new
// mechanism.  SQ_LDS_BANK_CONFLICT ~6.29M = inherent wave64 b128 issue cost
// (4/read, banks already even at 8/bank) — not fixable, not worth chasing.
// mode 0: N=3072 fused QKV -> scatter Q(bf16, *0.125*log2e)/K(bf16)/V^T(bf16)
// mode 1: N=1024 -> bf16 Yb[m*1024+n]
// ---------------------------------------------------------------------------
__global__ __launch_bounds__(256)
void gemm_mfma(const ushort_t* __restrict__ A, const ushort_t* __restrict__ Bw,
               const float* __restrict__ bias0, const float* __restrict__ bias1,
               const float* __restrict__ bias2,
               ushort_t* __restrict__ Yb, ushort_t* __restrict__ Qo,
               ushort_t* __restrict__ Ko, ushort_t* __restrict__ Vo,
               int K, int mode)
{
    __shared__ __align__(16) ushort_t As[3][128 * 32];
    __shared__ __align__(16) ushort_t Bs[3][128 * 32];
    const int t = threadIdx.x;
    const int lane = t & 63, wave = t >> 6;
    const int wm = wave >> 1, wn = wave & 1;
    const int m0 = blockIdx.x * 128, n0 = blockIdx.y * 128;
    const int quad = lane >> 4, l15 = lane & 15;

    const int ch0 = wave * 2, ch1 = wave * 2 + 1;
    const int srow = lane >> 2;                        // 0..15
    const int scol = 8 * ((lane & 3) ^ (srow & 3));    // swizzled 16B slot
    const ushort_t* Ap0 = A  + (size_t)(m0 + ch0 * 16 + srow) * K + scol;
    const ushort_t* Ap1 = A  + (size_t)(m0 + ch1 * 16 + srow) * K + scol;
    const ushort_t* Bp0 = Bw + (size_t)(n0 + ch0 * 16 + srow) * K + scol;
    const ushort_t* Bp1 = Bw + (size_t)(n0 + ch1 * 16 + srow) * K + scol;

    f32x4 acc[4][4] = {};

    // prefetch slabs 0,1 into buffers 0,1
    GLD16(Ap0, As[0] + ch0 * 512);
    GLD16(Ap1, As[0] + ch1 * 512);
    GLD16(Bp0, Bs[0] + ch0 * 512);
    GLD16(Bp1, Bs[0] + ch1 * 512);
    GLD16(Ap0 + 32, As[1] + ch0 * 512);
    GLD16(Ap1 + 32, As[1] + ch1 * 512);
    GLD16(Bp0 + 32, Bs[1] + ch0 * 512);
    GLD16(Bp1 + 32, Bs[1] + ch1 * 512);

    // frag-read slot offset: logical slot = quad, phys = quad ^ (row&3);
    // row = 16*i + l15 -> row&3 = l15&3.
    const int skq = 8 * (quad ^ (l15 & 3));

    const int nk = K >> 5;
    for (int ki = 0; ki < nk; ki++) {
        const int buf = ki % 3;
        if (ki + 2 < nk) {
            const int k2 = (ki + 2) << 5;
            const int b2 = (ki + 2) % 3;
            GLD16(Ap0 + k2, As[b2] + ch0 * 512);
            GLD16(Ap1 + k2, As[b2] + ch1 * 512);
            GLD16(Bp0 + k2, Bs[b2] + ch0 * 512);
            GLD16(Bp1 + k2, Bs[b2] + ch1 * 512);
            WAIT_VM8();     // own slab-ki loads landed; 8 (2 slabs) in flight
        } else if (ki + 1 < nk) {
            WAIT_VM4();
        } else {
            WAIT_VM0();
        }
        BAR();

        bf16x8 af[4], bfr[4];
        #pragma unroll
        for (int i = 0; i < 4; i++)
            af[i] = *(const bf16x8*)(As[buf] + (64 * wm + 16 * i + l15) * 32 + skq);
        #pragma unroll
        for (int j = 0; j < 4; j++)
            bfr[j] = *(const bf16x8*)(Bs[buf] + (64 * wn + 16 * j + l15) * 32 + skq);
        #pragma unroll
        for (int i = 0; i < 4; i++)
            #pragma unroll
            for (int j = 0; j < 4; j++)
                acc[i][j] = __builtin_amdgcn_mfma_f32_16x16x32_bf16(af[i], bfr[j], acc[i][j], 0, 0, 0);

        BAR();    // all reads of buf done before overwrite
    }

    // epilogue — C/D layout: row = quad*4+r, col = l15
    #pragma unroll
    for (int j = 0; j < 4; j++) {
        const int n = n0 + 64 * wn + 16 * j + l15;
        if (mode == 1) {
            const float bv = bias0[n];
            #pragma unroll
            for (int i = 0; i < 4; i++) {
                const int mrow = m0 + 64 * wm + 16 * i + quad * 4;
                ushort_t* yp = Yb + (size_t)mrow * D_ + n;
                #pragma unroll
                for (int r = 0; r < 4; r++)
                    yp[(size_t)r * D_] = f2bf(acc[i][j][r] + bv);
            }
        } else {
            const int sel = n >> 10, nn = n & 1023;
            const int hh = nn >> 6, dd = nn & 63;
            const float bv = (sel == 0 ? bias0 : (sel == 1 ? bias1 : bias2))[nn];
            // Q pre-scaled by 0.125*log2(e) so attention exp is exp2-native
            const float scl = (sel == 0) ? 0.18033688f : 1.0f;
            #pragma unroll
            for (int i = 0; i < 4; i++) {
                const int mrow = m0 + 64 * wm + 16 * i + quad * 4;
                const int b = mrow >> 11;
                const int ss = mrow & (S_ - 1);
                if (sel == 2) {
                    // V^T [B,H,dh,S]: r is contiguous -> one us4 store
                    us4 pk;
                    #pragma unroll
                    for (int r = 0; r < 4; r++)
                        pk[r] = f2bf(acc[i][j][r] + bv);
                    *(us4*)(Vo + (((size_t)b * H_ + hh) * DH_ + dd) * S_ + ss) = pk;
                } else {
                    ushort_t* dst = (sel == 0) ? Qo : Ko;
                    #pragma unroll
                    for (int r = 0; r < 4; r++) {
                        const float v = (acc[i][j][r] + bv) * scl;
                        dst[(((size_t)b * H_ + hh) * S_ + ss + r) * DH_ + dd] = f2bf(v);
                    }
                }
            }
        }
    }
}

// ---------------------------------------------------------------------------
// MFMA flash attention (causal), transposed-score, STATIC-MAX softmax.
//   S^T = K·Q^T  (C/D: row=key=quad*4+r, col=query=l15);  O^T = V^T·P^T.
// Q pre-scaled by 0.125*log2e -> p = exp2(s' - 16) via accumulator init -16.
// R7: reverted to the R1-proven global_load_lds double-buffer form.  R6's
// reg-staged single-buffer spilled (WRITE_SIZE 16->459MB scratch traffic,
// 72->232us): kf+vf+sc+o+qf+prefetch ≈ 170 VGPR vs the (256,4) cap of 128.
// Reg-staging is off the table for this kernel's register budget.
// Grid 64 x 16: x = bh (L2 locality), y -> qt = 15 - y (longest first).
// 1024 blocks -> 3 blocks/CU resident (LDS 50KB).
// ---------------------------------------------------------------------------
__global__ __launch_bounds__(256, 3)
void attn_mfma(const ushort_t* __restrict__ Qb, const ushort_t* __restrict__ Kb,
               const ushort_t* __restrict__ Vt, ushort_t* __restrict__ outb)
{
    __shared__ __align__(16) ushort_t Ks[2][64 * 64];
    __shared__ __align__(16) ushort_t Vs[2][64 * 64];
    __shared__ __align__(16) ushort_t Ps[8][16 * 72];   // [wave*2+g][16q][64k+pad]
    const int t = threadIdx.x, lane = t & 63, w = t >> 6;
    const int bh = blockIdx.x;             // 0..63  (b*16+h)
    const int qt = 15 - (int)blockIdx.y;   // longest first
    const int quad = lane >> 4, l15 = lane & 15;
    const int rw = 32 * w;                 // wave's first query within q-tile

    const int c0 = 2 * w, c1 = 2 * w + 1;
    const int srow = lane >> 3;                   // 0..7 row within chunk
    const int scol = 8 * ((lane & 7) ^ srow);     // XOR-8 swizzled col (ushort)
    const ushort_t* KgB = Kb + (size_t)bh * S_ * DH_;
    const ushort_t* VgB = Vt + (size_t)bh * DH_ * S_;
    const ushort_t* Kg0 = KgB + (size_t)(c0 * 8 + srow) * DH_ + scol;
    const ushort_t* Kg1 = KgB + (size_t)(c1 * 8 + srow) * DH_ + scol;
    const ushort_t* Vg0 = VgB + (size_t)(c0 * 8 + srow) * S_ + scol;
    const ushort_t* Vg1 = VgB + (size_t)(c1 * 8 + srow) * S_ + scol;
    ushort_t* pw0 = Ps[w * 2 + 0];
    ushort_t* pw1 = Ps[w * 2 + 1];
    const int b = bh >> 4, hh = bh & (H_ - 1);

    const int q0 = qt * 128;

    const ushort_t* qp = Qb + ((size_t)bh * S_ + q0 + rw + l15) * DH_ + quad * 8;
    const bf16x8 qf00 = *(const bf16x8*)(qp);
    const bf16x8 qf01 = *(const bf16x8*)(qp + 32);
    const bf16x8 qf10 = *(const bf16x8*)(qp + 16 * DH_);
    const bf16x8 qf11 = *(const bf16x8*)(qp + 16 * DH_ + 32);

    f32x4 o0[4] = {}, o1[4] = {};
    float la0 = 0.f, la1 = 0.f;        // per-lane partial row-sum of P

    WAIT_VM0();      // Q frags resident; vmcnt bookkeeping exact from here
    MEMFENCE();
    GLD16(Kg0, &Ks[0][c0 * 512]);
    GLD16(Kg1, &Ks[0][c1 * 512]);
    GLD16(Vg0, &Vs[0][c0 * 512]);
    GLD16(Vg1, &Vs[0][c1 * 512]);

    const int qg00 = q0 + rw;          // g=0 first query
    const int qg10 = q0 + rw + 16;     // g=1 first query
    const int last = 2 * qt + 1;

    for (int kt = 0; kt <= last; kt++) {
        const int buf = kt & 1;
        const int k0 = kt * 64;
        if (kt < last) {
            const size_t ko = (size_t)(k0 + 64) * DH_;
            GLD16(Kg0 + ko, &Ks[buf ^ 1][c0 * 512]);
            GLD16(Kg1 + ko, &Ks[buf ^ 1][c1 * 512]);
            GLD16(Vg0 + k0 + 64, &Vs[buf ^ 1][c0 * 512]);
            GLD16(Vg1 + k0 + 64, &Vs[buf ^ 1][c1 * 512]);
            WAIT_VM4();
        } else {
            WAIT_VM0();
        }
        BAR();

        if (k0 <= qg10 + 15) {         // wave has at least one unmasked query
            const bool a0 = (k0 <= qg00 + 15);
            const ushort_t* kb = Ks[buf];
            const ushort_t* vb = Vs[buf];
            const int xr = l15 & 7;    // swizzle term (row&7) for frag reads

            bf16x8 kf[4][2];
            #pragma unroll
            for (int ct = 0; ct < 4; ct++)
                #pragma unroll
                for (int h = 0; h < 2; h++)
                    kf[ct][h] = *(const bf16x8*)(kb + (ct * 16 + l15) * 64 +
                                                 8 * ((h * 4 + quad) ^ xr));

            // scores with C preloaded to -16 (static softmax shift)
            const f32x4 cinit = { -16.f, -16.f, -16.f, -16.f };
            f32x4 sc0[4], sc1[4];
            #pragma unroll
            for (int ct = 0; ct < 4; ct++) { sc0[ct] = cinit; sc1[ct] = cinit; }
            __builtin_amdgcn_s_setprio(1);
            #pragma unroll
            for (int ct = 0; ct < 4; ct++) {
                sc1[ct] = __builtin_amdgcn_mfma_f32_16x16x32_bf16(kf[ct][0], qf10, sc1[ct], 0, 0, 0);
                sc1[ct] = __builtin_amdgcn_mfma_f32_16x16x32_bf16(kf[ct][1], qf11, sc1[ct], 0, 0, 0);
            }
            if (a0) {
                #pragma unroll
                for (int ct = 0; ct < 4; ct++) {
                    sc0[ct] = __builtin_amdgcn_mfma_f32_16x16x32_bf16(kf[ct][0], qf00, sc0[ct], 0, 0, 0);
                    sc0[ct] = __builtin_amdgcn_mfma_f32_16x16x32_bf16(kf[ct][1], qf01, sc0[ct], 0, 0, 0);
                }
            }
            __builtin_amdgcn_s_setprio(0);

            bf16x8 vf[4][2];
            #pragma unroll
            for (int mt = 0; mt < 4; mt++)
                #pragma unroll
                for (int h = 0; h < 2; h++)
                    vf[mt][h] = *(const bf16x8*)(vb + (mt * 16 + l15) * 64 +
                                                 8 * ((h * 4 + quad) ^ xr));

            if (k0 + 63 > qg10) {      // causal mask: diagonal band only
                const int qq = qg10 + l15;
                #pragma unroll
                for (int ct = 0; ct < 4; ct++) {
                    const int key = k0 + ct * 16 + quad * 4;
                    #pragma unroll
                    for (int r = 0; r < 4; r++)
                        if (key + r > qq) sc1[ct][r] = -1e30f;
                }
            }
            if (a0 && k0 + 63 > qg00) {
                const int qq = qg00 + l15;
                #pragma unroll
                for (int ct = 0; ct < 4; ct++) {
                    const int key = k0 + ct * 16 + quad * 4;
                    #pragma unroll
                    for (int r = 0; r < 4; r++)
                        if (key + r > qq) sc0[ct][r] = -1e30f;
                }
            }

            // p = exp2(score - 16); accumulate per-lane l; truncation-pack
            #pragma unroll
            for (int ct = 0; ct < 4; ct++) {
                us4 pk;
                #pragma unroll
                for (int r = 0; r < 4; r++) {
                    const float p = exp2f(sc1[ct][r]);
                    la1 += p;
                    pk[r] = (ushort_t)(__float_as_uint(p) >> 16);
                }
                *(us4*)(pw1 + l15 * 72 + ct * 16 + quad * 4) = pk;
            }
            if (a0) {
                #pragma unroll
                for (int ct = 0; ct < 4; ct++) {
                    us4 pk;
                    #pragma unroll
                    for (int r = 0; r < 4; r++) {
                        const float p = exp2f(sc0[ct][r]);
                        la0 += p;
                        pk[r] = (ushort_t)(__float_as_uint(p) >> 16);
                    }
                    *(us4*)(pw0 + l15 * 72 + ct * 16 + quad * 4) = pk;
                }
            }

            // O^T += V^T · P^T  (B-frag: n=query=l15, k=key=h*32+quad*8+j)
            __builtin_amdgcn_s_setprio(1);
            const bf16x8 pf10 = *(const bf16x8*)(pw1 + l15 * 72 + quad * 8);
            const bf16x8 pf11 = *(const bf16x8*)(pw1 + l15 * 72 + 32 + quad * 8);
            #pragma unroll
            for (int mt = 0; mt < 4; mt++) {
                o1[mt] = __builtin_amdgcn_mfma_f32_16x16x32_bf16(vf[mt][0], pf10, o1[mt], 0, 0, 0);
                o1[mt] = __builtin_amdgcn_mfma_f32_16x16x32_bf16(vf[mt][1], pf11, o1[mt], 0, 0, 0);
            }
            if (a0) {
                const bf16x8 pf00 = *(const bf16x8*)(pw0 + l15 * 72 + quad * 8);
                const bf16x8 pf01 = *(const bf16x8*)(pw0 + l15 * 72 + 32 + quad * 8);
                #pragma unroll
                for (int mt = 0; mt < 4; mt++) {
                    o0[mt] = __builtin_amdgcn_mfma_f32_16x16x32_bf16(vf[mt][0], pf00, o0[mt], 0, 0, 0);
                    o0[mt] = __builtin_amdgcn_mfma_f32_16x16x32_bf16(vf[mt][1], pf01, o0[mt], 0, 0, 0);
                }
            }
            __builtin_amdgcn_s_setprio(0);
        }
        BAR();    // all reads of buf done before overwrite
    }

    // epilogue: reduce l across quads once; normalize; bf16 stores
    {
        la0 += __shfl_xor(la0, 16);
        la1 += __shfl_xor(la1, 16);
        la0 += __shfl_xor(la0, 32);
        la1 += __shfl_xor(la1, 32);
        const float inv0 = 1.0f / la0, inv1 = 1.0f / la1;
        const int query0 = q0 + rw + l15;
        ushort_t* ob0 = outb + ((size_t)(b * S_ + query0)) * D_ + hh * DH_ + quad * 4;
        ushort_t* ob1 = ob0 + (size_t)16 * D_;
        #pragma unroll
        for (int mt = 0; mt < 4; mt++) {
            us4 r0, r1;
            #pragma unroll
            for (int r = 0; r < 4; r++) {
                r0[r] = f2bf(o0[mt][r] * inv0);
                r1[r] = f2bf(o1[mt][r] * inv1);
            }
            *(us4*)(ob0 + mt * 16) = r0;
            *(us4*)(ob1 + mt * 16) = r1;
        }
    }
}

// ---------------------------------------------------------------------------
// LN1: out_bf = LayerNorm(X_f32 + R_bf16) * g + b   (bf16 output only)
// R6-keep: wave-per-row (4 rows/block, grid 2048), no LDS, no syncthreads,
// __shfl_xor butterfly.  Saved ~12us vs the 2-stage LDS-reduction version.
// ---------------------------------------------------------------------------
__global__ __launch_bounds__(256)
void ln_f32bf(const float* __restrict__ X, const ushort_t* __restrict__ R,
              const float* __restrict__ g, const float* __restrict__ bia,
              ushort_t* __restrict__ out_bf)
{
    const int wid = threadIdx.x >> 6, lane = threadIdx.x & 63;
    const int row = blockIdx.x * 4 + wid;
    const float*   xr = X + (size_t)row * D_;
    const ushort_t* rr = R + (size_t)row * D_;

    float s[16];
    float sum = 0.f, sq = 0.f;
    #pragma unroll
    for (int k = 0; k < 4; k++) {
        const int off = k * 256 + lane * 4;
        const float4 xv = *(const float4*)(xr + off);
        const us4    rv = *(const us4*)(rr + off);
        const float v0 = xv.x + bf2f(rv[0]);
        const float v1 = xv.y + bf2f(rv[1]);
        const float v2 = xv.z + bf2f(rv[2]);
        const float v3 = xv.w + bf2f(rv[3]);
        s[k*4+0] = v0; s[k*4+1] = v1; s[k*4+2] = v2; s[k*4+3] = v3;
        sum += v0 + v1 + v2 + v3;
        sq  += v0*v0 + v1*v1 + v2*v2 + v3*v3;
    }
    #pragma unroll
    for (int off = 1; off < 64; off <<= 1) {
        sum += __shfl_xor(sum, off);
        sq  += __shfl_xor(sq,  off);
    }
    const float mean = sum * (1.0f / D_);
    const float inv  = rsqrtf(sq * (1.0f / D_) - mean * mean + 1e-5f);

    ushort_t* orow = out_bf + (size_t)row * D_;
    #pragma unroll
    for (int k = 0; k < 4; k++) {
        const int off = k * 256 + lane * 4;
        const float4 gv = *(const float4*)(g + off);
        const float4 bv = *(const float4*)(bia + off);
        us4 ob;
        ob[0] = f2bf((s[k*4+0] - mean) * inv * gv.x + bv.x);
        ob[1] = f2bf((s[k*4+1] - mean) * inv * gv.y + bv.y);
        ob[2] = f2bf((s[k*4+2] - mean) * inv * gv.z + bv.z);
        ob[3] = f2bf((s[k*4+3] - mean) * inv * gv.w + bv.w);
        *(us4*)(orow + off) = ob;
    }
}

// ---------------------------------------------------------------------------
// LN2: out_f32 = LayerNorm(Hb_bf16 + Yb_bf16) * g + b   (wave-per-row)
// ---------------------------------------------------------------------------
__global__ __launch_bounds__(256)
void ln_bfbf(const ushort_t* __restrict__ Hb, const ushort_t* __restrict__ Yb,
             const float* __restrict__ g, const float* __restrict__ bia,
             float* __restrict__ outf)
{
    const int wid = threadIdx.x >> 6, lane = threadIdx.x & 63;
    const int row = blockIdx.x * 4 + wid;
    const ushort_t* hr = Hb + (size_t)row * D_;
    const ushort_t* yr = Yb + (size_t)row * D_;

    float s[16];
    float sum = 0.f, sq = 0.f;
    #pragma unroll
    for (int k = 0; k < 4; k++) {
        const int off = k * 256 + lane * 4;
        const us4 hv = *(const us4*)(hr + off);
        const us4 yv = *(const us4*)(yr + off);
        const float v0 = bf2f(hv[0]) + bf2f(yv[0]);
        const float v1 = bf2f(hv[1]) + bf2f(yv[1]);
        const float v2 = bf2f(hv[2]) + bf2f(yv[2]);
        const float v3 = bf2f(hv[3]) + bf2f(yv[3]);
        s[k*4+0] = v0; s[k*4+1] = v1; s[k*4+2] = v2; s[k*4+3] = v3;
        sum += v0 + v1 + v2 + v3;
        sq  += v0*v0 + v1*v1 + v2*v2 + v3*v3;
    }
    #pragma unroll
    for (int off = 1; off < 64; off <<= 1) {
        sum += __shfl_xor(sum, off);
        sq  += __shfl_xor(sq,  off);
    }
    const float mean = sum * (1.0f / D_);
    const float inv  = rsqrtf(sq * (1.0f / D_) - mean * mean + 1e-5f);

    float* orow = outf + (size_t)row * D_;
    #pragma unroll
    for (int k = 0; k < 4; k++) {
        const int off = k * 256 + lane * 4;
        const float4 gv = *(const float4*)(g + off);
        const float4 bv = *(const float4*)(bia + off);
        float4 o;
        o.x = (s[k*4+0] - mean) * inv * gv.x + bv.x;
        o.y = (s[k*4+1] - mean) * inv * gv.y + bv.y;
        o.z = (s[k*4+2] - mean) * inv * gv.z + bv.z;
        o.w = (s[k*4+3] - mean) * inv * gv.w + bv.w;
        *(float4*)(orow + off) = o;
    }
}

// ---------------------------------------------------------------------------
extern "C" void kernel_launch(void* const* d_in, const int* in_sizes, int n_in,
                              void* d_out, int out_size, void* d_ws, size_t ws_size,
                              hipStream_t stream)
{
    const float* x      = (const float*)d_in[0];
    const float* wq_w   = (const float*)d_in[1];
    const float* wq_b   = (const float*)d_in[2];
    const float* wk_w   = (const float*)d_in[3];
    const float* wk_b   = (const float*)d_in[4];
    const float* wv_w   = (const float*)d_in[5];
    const float* wv_b   = (const float*)d_in[6];
    const float* ln1_g  = (const float*)d_in[7];
    const float* ln1_b  = (const float*)d_in[8];
    const float* lin1_w = (const float*)d_in[9];
    const float* lin1_b = (const float*)d_in[10];
    const float* ln2_g  = (const float*)d_in[11];
    const float* ln2_b  = (const float*)d_in[12];
    float* out = (float*)d_out;

    char* base = (char*)d_ws;
    // ws layout (aliased through the pipeline):
    //   [0   ,16M): x_bf   -> attn_bf (x_bf dead after QKV GEMM)
    //   [16M ,24M): w_bf (wq|wk|wv|lin1)
    //   [24M ,40M): Qbf  -> h_bf   (Qbf dead after attention)
    //   [40M ,56M): Kbf  -> y_bf   (Kbf dead after attention)
    //   [56M ,72M): Vtp
    ushort_t* x_bf    = (ushort_t*)(base);
    ushort_t* attn_bf = (ushort_t*)(base);
    ushort_t* w_bf    = (ushort_t*)(base + 16777216);
    ushort_t* Qbf     = (ushort_t*)(base + 25165824);
    ushort_t* h_bf    = (ushort_t*)(base + 25165824);
    ushort_t* Kbf     = (ushort_t*)(base + 41943040);
    ushort_t* y_bf    = (ushort_t*)(base + 41943040);
    ushort_t* Vtp     = (ushort_t*)(base + 58720256);

    cvt_all<<<dim3(4096 + 4 * 512), 256, 0, stream>>>(
        x, wq_w, wk_w, wv_w, lin1_w, x_bf, w_bf);

    gemm_mfma<<<dim3(M_ / 128, 3072 / 128), 256, 0, stream>>>(
        x_bf, w_bf, wq_b, wk_b, wv_b, nullptr, Qbf, Kbf, Vtp, D_, 0);

    attn_mfma<<<dim3(64, 16), 256, 0, stream>>>(Qbf, Kbf, Vtp, attn_bf);

    ln_f32bf<<<dim3(M_ / 4), 256, 0, stream>>>(x, attn_bf, ln1_g, ln1_b, h_bf);

    gemm_mfma<<<dim3(M_ / 128, D_ / 128), 256, 0, stream>>>(
        h_bf, w_bf + 3 * D_ * D_, lin1_b, nullptr, nullptr, y_bf, nullptr, nullptr, nullptr, D_, 1);

    ln_bfbf<<<dim3(M_ / 4), 256, 0, stream>>>(h_bf, y_bf, ln2_g, ln2_b, out);
}